// Round 1
// 629.238 us; speedup vs baseline: 1.0904x; 1.0904x over previous
//
#include <hip/hip_runtime.h>
#include <hip/hip_bf16.h>

#define DEV __device__ __forceinline__

typedef __attribute__((ext_vector_type(8))) short bf16x8;
typedef __attribute__((ext_vector_type(4))) float f32x4;

constexpr int Bb = 2, V = 65536, CIN = 128, COUT = 256, TDIM = 512;
constexpr float EPS = 1e-5f;
constexpr int K1 = 1152, K2 = 2304, K2e = 2432;
constexpr int NCH1 = 128;   // gn1 chunks (512 rows each)
constexpr int NCH2 = 256;   // gn2 chunks (256 rows each)
constexpr int W1N = (K1/8)*COUT*8;    // 294912
constexpr int W2N = (K2e/8)*COUT*8;   // 622592

DEV float silu_f(float x){ return x / (1.f + __expf(-x)); }
DEV unsigned short f2b(float x){
  union { float f; unsigned u; } v; v.f = x;
  unsigned r = v.u + 0x7fffu + ((v.u >> 16) & 1u);
  return (unsigned short)(r >> 16);
}
DEV float b2f(unsigned short h){ union { unsigned u; float f; } v; v.u = ((unsigned)h) << 16; return v.f; }

// ---------------- gn1 stats ----------------
__global__ void k_gn1_partial(const float* __restrict__ x, float* __restrict__ part){
  int b = blockIdx.y, ch = blockIdx.x;
  int t = threadIdx.x;            // 256
  int c = t & 127;
  int r0 = t >> 7;                // 0..1
  float s = 0.f, ss = 0.f;
  const float* xp = x + ((size_t)b*V + (size_t)ch*512)*CIN + c;
  for (int r = r0; r < 512; r += 2){
    float v = xp[(size_t)r*CIN];
    s += v; ss += v*v;
  }
  __shared__ float s_s[256], s_q[256];
  s_s[t] = s; s_q[t] = ss; __syncthreads();
  if (t < 128){ s_s[t] += s_s[t+128]; s_q[t] += s_q[t+128]; }
  __syncthreads();
  if (t < 32){
    float a = 0, q = 0;
    for (int i = 0; i < 4; ++i){ a += s_s[t*4+i]; q += s_q[t*4+i]; }
    int idx = ((b*32 + t)*NCH1 + ch)*2;
    part[idx] = a; part[idx+1] = q;
  }
}

__global__ void k_gn1_final(const float* __restrict__ part, const float* __restrict__ w,
                            const float* __restrict__ bias, float* __restrict__ sc,
                            float* __restrict__ bi){
  int t = threadIdx.x;  // 64 = b*32+g
  if (t >= Bb*32) return;
  float s = 0, q = 0;
  for (int ch = 0; ch < NCH1; ++ch){ s += part[(t*NCH1+ch)*2]; q += part[(t*NCH1+ch)*2+1]; }
  float n = (float)V * 4.f;
  float mean = s / n;
  float var = q / n - mean*mean;
  float inv = rsqrtf(var + EPS);
  int b = t >> 5, g = t & 31;
  for (int j = 0; j < 4; ++j){
    int c = g*4 + j;
    float scl = w[c] * inv;
    sc[b*CIN + c] = scl;
    bi[b*CIN + c] = bias[c] - mean*scl;
  }
}

// act1 = bf16(silu(gn1(x))), xb = bf16(x)
__global__ void k_act1(const float* __restrict__ x, const float* __restrict__ sc,
                       const float* __restrict__ bi, unsigned short* __restrict__ act1,
                       unsigned short* __restrict__ xb){
  size_t i = ((size_t)blockIdx.x*256 + threadIdx.x)*4;
  int c = (int)(i & (CIN-1));
  int b = (int)(i >> 23);
  float4 v = *(const float4*)(x + i);
  const float* scp = sc + b*CIN + c;
  const float* bip = bi + b*CIN + c;
  ushort4 a, xo;
  a.x = f2b(silu_f(v.x*scp[0] + bip[0]));
  a.y = f2b(silu_f(v.y*scp[1] + bip[1]));
  a.z = f2b(silu_f(v.z*scp[2] + bip[2]));
  a.w = f2b(silu_f(v.w*scp[3] + bip[3]));
  xo.x = f2b(v.x); xo.y = f2b(v.y); xo.z = f2b(v.z); xo.w = f2b(v.w);
  *(ushort4*)(act1 + i) = a;
  *(ushort4*)(xb + i)   = xo;
}

// W layouts: Wb[k8][o][j] = W[o][k8*8+j], bf16. W2b gets ws appended at k>=2304.
__global__ void k_prepW(const float* __restrict__ w1, const float* __restrict__ w2,
                        const float* __restrict__ wsm, unsigned short* __restrict__ W1b,
                        unsigned short* __restrict__ W2b){
  int i = blockIdx.x*256 + threadIdx.x;
  if (i < W1N){
    int j = i & 7, o = (i >> 3) & 255, k8 = i >> 11;
    W1b[i] = f2b(w1[o*K1 + k8*8 + j]);
  }
  int i2 = i - W1N;
  if (i2 >= 0 && i2 < W2N){
    int j = i2 & 7, o = (i2 >> 3) & 255, k8 = i2 >> 11;
    int k = k8*8 + j;
    float v = (k < K2) ? w2[o*K2 + k] : wsm[o*CIN + (k - K2)];
    W2b[i2] = f2b(v);
  }
}

// tcomb[b][o] = silu(t_emb[b]) @ wt[o] + bt[o] + b1[o]
// One wave per output: coalesced wt reads + shuffle reduce (old version: 2 blocks,
// fully uncoalesced wt access).
__global__ void k_tcomb(const float* __restrict__ temb, const float* __restrict__ wt,
                        const float* __restrict__ bt, const float* __restrict__ b1,
                        float* __restrict__ tc){
  int b = blockIdx.y;
  int o = blockIdx.x*4 + (threadIdx.x >> 6);
  int l = threadIdx.x & 63;
  const float* tb = temb + (size_t)b*TDIM;
  const float* wr = wt + (size_t)o*TDIM;
  float acc = 0.f;
  #pragma unroll
  for (int k = l; k < TDIM; k += 64)
    acc += silu_f(tb[k]) * wr[k];
  #pragma unroll
  for (int off = 32; off > 0; off >>= 1) acc += __shfl_down(acc, off, 64);
  if (l == 0) tc[b*COUT + o] = acc + bt[o] + b1[o];
}

// ---------------- gathered GEMM, pipelined (counted-vmcnt double buffer) -------
// Tile: 128(M) x 128(N), 4 waves, BK=64, 16x16x32 bf16 MFMA.
// Pipeline (T3/T4 minimum form): double-buffered A/B LDS; each iteration issues
// the NEXT chunk's 8 global_load_lds, then waits s_waitcnt vmcnt(8) (exactly the
// 8 just-issued stay in flight; the previous chunk's 8 are retired) + raw
// s_barrier, then computes. __syncthreads() is NOT used in the loop: it would
// emit vmcnt(0) and drain the prefetch (m99/m100 null result).
// Hazards: RAW on buf[cur] <- vmcnt(8)+barrier; WAR on buf[cur^1] <- trailing
// barrier of previous iteration (all ds_reads consumed by MFMA-lgkmcnt before it).
// XCD pair swizzle: blocks (bx,n0=0) and (bx,n0=128) gather the SAME 128x9
// random rows; map them 8 dispatches apart (same XCD, ~same time) so the
// second one's A-gathers hit that XCD's L2.
// global_load_lds semantics: per-lane SOURCE addr; LDS dst = uniform base
// + lane*16B (m104/m108). A-LDS: XOR segment swizzle, slot s of row r holds
// global segment s^(r&7).
template<int CINR, int NCHUNK, int CPN, bool CONV2>
__launch_bounds__(256)
__global__ void k_conv(const unsigned short* __restrict__ act,
                       const unsigned short* __restrict__ xb,
                       const unsigned short* __restrict__ Wb,
                       const int* __restrict__ neigh,
                       const float* __restrict__ tc,
                       const float* __restrict__ b2,
                       const float* __restrict__ bs,
                       unsigned short* __restrict__ outb,
                       float* __restrict__ outf){
  __shared__ __align__(16) unsigned short A_lds[2][128*64];
  __shared__ __align__(16) unsigned short B_lds[2][64*128];
  __shared__ int nb[128*9];
  const int tid = threadIdx.x;
  const int w = tid >> 6, lane = tid & 63;
  const int d = blockIdx.x;                    // 0..2047
  const int bx = ((d >> 4) << 3) + (d & 7);    // row-block 0..1023
  const int n0 = ((d >> 3) & 1) << 7;          // N-half; pair is d..d+8 -> same XCD
  const int vflat = bx << 7;
  const int b = vflat >> 16;          // / V
  const int vb = vflat & (V-1);
  for (int i = tid; i < 128*9; i += 256) nb[i] = neigh[(size_t)vb*9 + i];

  f32x4 acc[4][4] = {};
  const int wm = w >> 1, wn = w & 1;
  const int quad = lane >> 4, l15 = lane & 15;
  const int sr = lane >> 3, ssg = lane & 7;

  const unsigned short* actb = act + (size_t)b*V*CINR;
  const unsigned short* xbb  = CONV2 ? (xb + (size_t)b*V*CIN) : (const unsigned short*)nullptr;

  auto STAGE = [&](int chunk, int buf){
    // A (gathered rows): 4 issues/wave, 8 rows x 8 segs each
    {
      int nidx = 0, c0, rl;
      const unsigned short* src;
      const bool scseg = CONV2 && (chunk >= NCHUNK-2);
      if (scseg){ c0 = (chunk - (NCHUNK-2))*64; src = xbb; rl = CIN; }
      else      { nidx = chunk / CPN; c0 = (chunk % CPN)*64; src = actb; rl = CINR; }
      #pragma unroll
      for (int i = 0; i < 4; ++i){
        int row  = (w<<5) + (i<<3) + sr;
        int rowg = scseg ? (vb + row) : nb[row*9 + nidx];
        int g = ssg ^ (row & 7);
        const unsigned short* gp = src + (size_t)rowg*rl + c0 + g*8;   // per-lane src
        unsigned short* lp = &A_lds[buf][((w<<5) + (i<<3))<<6];        // uniform dst
        __builtin_amdgcn_global_load_lds(gp, lp, 16, 0, 0);
      }
    }
    // B: [q8][n][8], 4 issues/wave (1 KB each)
    {
      const unsigned short* wsrc = Wb + (size_t)chunk*8*COUT*8;
      #pragma unroll
      for (int i = 0; i < 4; ++i){
        int e = (w<<2) + i;
        int q8 = e >> 1, nh = e & 1;
        const unsigned short* gp = wsrc + ((size_t)q8*COUT + n0 + (nh<<6) + lane)*8;
        unsigned short* lp = &B_lds[buf][q8*1024 + (nh<<9)];
        __builtin_amdgcn_global_load_lds(gp, lp, 16, 0, 0);
      }
    }
  };

  auto COMPUTE = [&](int cur){
    __builtin_amdgcn_s_setprio(1);
    #pragma unroll
    for (int ks = 0; ks < 2; ++ks){
      bf16x8 av[4], bv[4];
      #pragma unroll
      for (int mt = 0; mt < 4; ++mt){
        int m = (wm<<6) + (mt<<4) + l15;
        int seg = ((ks<<2) + quad) ^ (l15 & 7);    // undo swizzle (m&7 == l15&7)
        av[mt] = *(const bf16x8*)&A_lds[cur][(m<<6) + (seg<<3)];
      }
      #pragma unroll
      for (int nt = 0; nt < 4; ++nt){
        int n = (wn<<6) + (nt<<4) + l15;
        bv[nt] = *(const bf16x8*)&B_lds[cur][(((ks<<2)+quad)<<10) + (n<<3)];
      }
      #pragma unroll
      for (int mt = 0; mt < 4; ++mt)
        #pragma unroll
        for (int nt = 0; nt < 4; ++nt)
          acc[mt][nt] = __builtin_amdgcn_mfma_f32_16x16x32_bf16(av[mt], bv[nt], acc[mt][nt], 0, 0, 0);
    }
    __builtin_amdgcn_s_setprio(0);
  };

  __syncthreads();          // nb visible; vmcnt fully drained -> counting starts clean
  STAGE(0, 0);              // 8 loads in flight (chunk 0)

  #pragma unroll 2
  for (int chunk = 0; chunk < NCHUNK-1; ++chunk){
    const int cur = chunk & 1;
    STAGE(chunk + 1, cur ^ 1);                       // 8 more in flight (<=16)
    asm volatile("s_waitcnt vmcnt(8)" ::: "memory"); // chunk's 8 retired
    __builtin_amdgcn_s_barrier();                    // raw: no drain
    asm volatile("" ::: "memory");
    COMPUTE(cur);
    asm volatile("" ::: "memory");
    __builtin_amdgcn_s_barrier();                    // all reads of buf[cur] done
    asm volatile("" ::: "memory");
  }
  // peeled last chunk: nothing left to prefetch
  asm volatile("s_waitcnt vmcnt(0)" ::: "memory");
  __builtin_amdgcn_s_barrier();
  asm volatile("" ::: "memory");
  COMPUTE((NCHUNK-1) & 1);

  // ---- epilogue: C/D layout col=lane&15, row=quad*4+reg (m89-verified)
  #pragma unroll
  for (int mt = 0; mt < 4; ++mt){
    #pragma unroll
    for (int nt = 0; nt < 4; ++nt){
      int col = n0 + (wn<<6) + (nt<<4) + l15;
      float bval = CONV2 ? (b2[col] + bs[col]) : tc[b*COUT + col];
      #pragma unroll
      for (int rg = 0; rg < 4; ++rg){
        int row = (wm<<6) + (mt<<4) + (quad<<2) + rg;
        size_t off = ((size_t)(vflat + row))*COUT + col;
        float v = acc[mt][nt][rg] + bval;
        if (CONV2) outf[off] = v;
        else       outb[off] = f2b(v);
      }
    }
  }
}

// ---------------- gn2 stats on bf16 h1 ----------------
__global__ void k_gn2_partial(const unsigned short* __restrict__ h1, float* __restrict__ part){
  int b = blockIdx.y, ch = blockIdx.x;
  int t = threadIdx.x;  // 256 = channel
  float s = 0.f, ss = 0.f;
  const unsigned short* p = h1 + ((size_t)b*V + (size_t)ch*256)*COUT + t;
  for (int r = 0; r < 256; ++r){
    float v = b2f(p[(size_t)r*COUT]);
    s += v; ss += v*v;
  }
  __shared__ float s_s[256], s_q[256];
  s_s[t] = s; s_q[t] = ss; __syncthreads();
  if (t < 32){
    float a = 0, q = 0;
    for (int i = 0; i < 8; ++i){ a += s_s[t*8+i]; q += s_q[t*8+i]; }
    int idx = ((b*32 + t)*NCH2 + ch)*2;
    part[idx] = a; part[idx+1] = q;
  }
}

__global__ void k_gn2_final(const float* __restrict__ part, const float* __restrict__ w,
                            const float* __restrict__ bias, float* __restrict__ sc,
                            float* __restrict__ bi){
  int t = threadIdx.x;
  if (t >= Bb*32) return;
  float s = 0, q = 0;
  for (int ch = 0; ch < NCH2; ++ch){ s += part[(t*NCH2+ch)*2]; q += part[(t*NCH2+ch)*2+1]; }
  float n = (float)V * 8.f;
  float mean = s / n, var = q / n - mean*mean, inv = rsqrtf(var + EPS);
  int b = t >> 5, g = t & 31;
  for (int j = 0; j < 8; ++j){
    int c = g*8 + j;
    float scl = w[c] * inv;
    sc[b*COUT + c] = scl;
    bi[b*COUT + c] = bias[c] - mean*scl;
  }
}

// act2 = silu(gn2(h1)) in place (bf16)
__global__ void k_act2(unsigned short* __restrict__ h1, const float* __restrict__ sc,
                       const float* __restrict__ bi){
  size_t i = ((size_t)blockIdx.x*256 + threadIdx.x)*4;
  int c = (int)(i & (COUT-1));
  int b = (int)(i >> 24);
  ushort4 h = *(ushort4*)(h1 + i);
  const float* scp = sc + b*COUT + c;
  const float* bip = bi + b*COUT + c;
  ushort4 o;
  o.x = f2b(silu_f(b2f(h.x)*scp[0] + bip[0]));
  o.y = f2b(silu_f(b2f(h.y)*scp[1] + bip[1]));
  o.z = f2b(silu_f(b2f(h.z)*scp[2] + bip[2]));
  o.w = f2b(silu_f(b2f(h.w)*scp[3] + bip[3]));
  *(ushort4*)(h1 + i) = o;
}

extern "C" void kernel_launch(void* const* d_in, const int* in_sizes, int n_in,
                              void* d_out, int out_size, void* d_ws, size_t ws_size,
                              hipStream_t stream){
  const float* x    = (const float*)d_in[0];
  const float* temb = (const float*)d_in[1];
  const int*   neigh= (const int*)d_in[2];
  const float* gn1w = (const float*)d_in[3];
  const float* gn1b = (const float*)d_in[4];
  const float* w1   = (const float*)d_in[5];
  const float* b1   = (const float*)d_in[6];
  const float* wt   = (const float*)d_in[7];
  const float* bt   = (const float*)d_in[8];
  const float* gn2w = (const float*)d_in[9];
  const float* gn2b = (const float*)d_in[10];
  const float* w2   = (const float*)d_in[11];
  const float* b2   = (const float*)d_in[12];
  const float* wsm  = (const float*)d_in[13];
  const float* bs   = (const float*)d_in[14];
  float* out = (float*)d_out;

  char* wsp = (char*)d_ws;
  unsigned short* act1 = (unsigned short*)(wsp);                       // 32 MiB
  unsigned short* xb   = (unsigned short*)(wsp + 33554432);            // 32 MiB
  unsigned short* h1   = (unsigned short*)(wsp + 67108864);            // 64 MiB
  unsigned short* W1b  = (unsigned short*)(wsp + 134217728);           // 589824 B
  unsigned short* W2b  = (unsigned short*)(wsp + 134217728 + 589824);  // 1245184 B
  char* p = wsp + 134217728 + 589824 + 1245184;
  float* tc    = (float*)p;  p += 2048;
  float* part1 = (float*)p;  p += (size_t)Bb*32*NCH1*2*4;
  float* part2 = (float*)p;  p += (size_t)Bb*32*NCH2*2*4;
  float* sc1   = (float*)p;  p += 1024;
  float* bi1   = (float*)p;  p += 1024;
  float* sc2   = (float*)p;  p += 2048;
  float* bi2   = (float*)p;  p += 2048;

  k_gn1_partial<<<dim3(NCH1, Bb), 256, 0, stream>>>(x, part1);
  k_gn1_final  <<<1, 64, 0, stream>>>(part1, gn1w, gn1b, sc1, bi1);
  k_act1       <<<16384, 256, 0, stream>>>(x, sc1, bi1, act1, xb);
  k_prepW      <<<(W1N + W2N)/256, 256, 0, stream>>>(w1, w2, wsm, W1b, W2b);
  k_tcomb      <<<dim3(COUT/4, Bb), 256, 0, stream>>>(temb, wt, bt, b1, tc);
  k_conv<128, 18, 2, false><<<2048, 256, 0, stream>>>(act1, nullptr, W1b, neigh, tc, nullptr, nullptr, h1, nullptr);
  k_gn2_partial<<<dim3(NCH2, Bb), 256, 0, stream>>>(h1, part2);
  k_gn2_final  <<<1, 64, 0, stream>>>(part2, gn2w, gn2b, sc2, bi2);
  k_act2       <<<32768, 256, 0, stream>>>(h1, sc2, bi2);
  k_conv<256, 38, 4, true><<<2048, 256, 0, stream>>>(h1, xb, W2b, neigh, nullptr, b2, bs, nullptr, out);
}